// Round 10
// baseline (161.210 us; speedup 1.0000x reference)
//
#include <hip/hip_runtime.h>

// Problem constants (fixed by setup_inputs): N=2048, B=64, H=W=4096, ks=8
#define GRIDN 64        // block positions per axis (H/B)
#define NCELLS 4096     // GRIDN*GRIDN
#define BVEC 8192       // float4 per block: 64*64*8/4
#define ROWSTRIDE4 8192 // float4 per dense row: W*ks/4

typedef float f32x4 __attribute__((ext_vector_type(4)));

// ---------------------------------------------------------------------------
// Single fused kernel, R9 structure (512-thread wgs, 8192 = 4096 cells x 2
// chunks). ROUND-10 DELTA: plain stores instead of nontemporal (isolated
// one-flag probe; NT loads kept). Everything else bit-identical to R9.
__global__ __launch_bounds__(512) void k_fused(const int* __restrict__ idxw,
                                               const f32x4* __restrict__ bv4,
                                               f32x4* __restrict__ out4,
                                               int N) {
    const int cell = blockIdx.x >> 1;
    const int chunk = blockIdx.x & 1;
    const int R = cell >> 6;
    const int C = cell & (GRIDN - 1);
    const int tid = threadIdx.x;
    const int w = tid >> 6;      // wave 0..7
    const int lane = tid & 63;

    __shared__ unsigned long long masks[32];
    __shared__ short list_s[2048];
    __shared__ int odd_or;
    __shared__ int cnt_s;

    if (tid == 0) { odd_or = 0; cnt_s = 0; }
    __syncthreads();

    // ---- phase 1: int32 interpretation + dtype detect ----
    int my_or = 0;
#pragma unroll
    for (int k = 0; k < 4; ++k) {
        const int n = w * 256 + k * 64 + lane;
        int2 p = ((const int2*)idxw)[n];  // words 2n, 2n+1
        my_or |= p.y;                      // odd word
        const bool match = (n < N) && (p.x == R) && (p.y == C);
        unsigned long long mk = __ballot(match);
        if (lane == 0) masks[w * 4 + k] = mk;
    }
    if (__any(my_or != 0) && lane == 0) odd_or = 1;  // benign multi-write
    __syncthreads();

    if (odd_or == 0) {  // int64 indices: redo ballots from 16B entries
#pragma unroll
        for (int k = 0; k < 4; ++k) {
            const int n = w * 256 + k * 64 + lane;
            int4 p = ((const int4*)idxw)[n];  // words 4n..4n+3
            const bool match = (n < N) && (p.x == R) && (p.z == C);
            unsigned long long mk = __ballot(match);
            if (lane == 0) masks[w * 4 + k] = mk;
        }
        __syncthreads();
    }

    // ---- parallel ordered extraction (wave 0, lanes 0..31) ----
    if (tid < 64) {
        unsigned long long mk = (lane < 32) ? masks[lane] : 0ULL;
        const int pc = __popcll(mk);
        int pre = pc;  // inclusive prefix over lanes 0..31
#pragma unroll
        for (int d = 1; d < 32; d <<= 1) {
            int v = __shfl_up(pre, d, 64);
            if (lane >= d) pre += v;
        }
        int pos = pre - pc;  // exclusive
        const int base = lane * 64;
        while (mk) {
            const int b = __ffsll(mk) - 1;
            list_s[pos++] = (short)(base + b);
            mk &= mk - 1;
        }
        if (lane == 31) cnt_s = pre;
    }
    __syncthreads();
    const int cnt = cnt_s;

    // ---- streaming (R9 structure; stores now PLAIN, loads still NT) ----
    const int tbase = chunk * 4096 + tid;
    const size_t obase = (size_t)(R * 64) * ROWSTRIDE4 + (size_t)C * 128;

    if (cnt == 0) {
        const f32x4 z = {0.f, 0.f, 0.f, 0.f};
#pragma unroll
        for (int i = 0; i < 8; ++i) {
            int t = tbase + i * 512;
            out4[obase + (size_t)(t >> 7) * ROWSTRIDE4 + (t & 127)] = z;
        }
    } else if (cnt == 1) {
        const f32x4* __restrict__ src = bv4 + (size_t)list_s[0] * BVEC;
#pragma unroll
        for (int i = 0; i < 8; ++i) {
            int t = tbase + i * 512;
            f32x4 v = __builtin_nontemporal_load(&src[t]);
            out4[obase + (size_t)(t >> 7) * ROWSTRIDE4 + (t & 127)] = v;
        }
    } else {
        f32x4 acc[8];
#pragma unroll
        for (int i = 0; i < 8; ++i) acc[i] = (f32x4){0.f, 0.f, 0.f, 0.f};
        for (int j = 0; j < cnt; ++j) {
            const f32x4* __restrict__ src = bv4 + (size_t)list_s[j] * BVEC;
#pragma unroll
            for (int i = 0; i < 8; ++i)
                acc[i] += __builtin_nontemporal_load(&src[tbase + i * 512]);
        }
#pragma unroll
        for (int i = 0; i < 8; ++i) {
            int t = tbase + i * 512;
            out4[obase + (size_t)(t >> 7) * ROWSTRIDE4 + (t & 127)] = acc[i];
        }
    }
}

// ---------------------------------------------------------------------------
extern "C" void kernel_launch(void* const* d_in, const int* in_sizes, int n_in,
                              void* d_out, int out_size, void* d_ws, size_t ws_size,
                              hipStream_t stream) {
    const float* bv = (const float*)d_in[0];
    const int* idxw = (const int*)d_in[1];
    const int N = in_sizes[1] / 2;  // 2048 blocks

    k_fused<<<NCELLS * 2, 512, 0, stream>>>(idxw, (const f32x4*)bv,
                                            (f32x4*)d_out, N);
}

// Round 11
// 156.473 us; speedup vs baseline: 1.0303x; 1.0303x over previous
//
#include <hip/hip_runtime.h>

// Problem constants (fixed by setup_inputs): N=2048, B=64, H=W=4096, ks=8
#define GRIDN 64        // block positions per axis (H/B)
#define NCELLS 4096     // GRIDN*GRIDN
#define BVEC 8192       // float4 per block: 64*64*8/4
#define ROWSTRIDE4 8192 // float4 per dense row: W*ks/4

typedef float f32x4 __attribute__((ext_vector_type(4)));

// ---------------------------------------------------------------------------
// Single fused kernel. ROUND-11 DELTA vs R9 (153.1 best): 1024-thread wgs,
// one wg per cell (grid 4096) -> index ballot-scan paid ONCE per cell
// (redundancy 2x -> 1x). NT stores restored (R10 proved plain stores cost
// +8 us). Per-thread streaming structure identical: 8x f32x4, same
// t->(row,slot) map, ascending-j summation => bit-identical output.
__global__ __launch_bounds__(1024) void k_fused(const int* __restrict__ idxw,
                                                const f32x4* __restrict__ bv4,
                                                f32x4* __restrict__ out4,
                                                int N) {
    const int cell = blockIdx.x;
    const int R = cell >> 6;
    const int C = cell & (GRIDN - 1);
    const int tid = threadIdx.x;
    const int w = tid >> 6;      // wave 0..15
    const int lane = tid & 63;

    __shared__ unsigned long long masks[32];
    __shared__ short list_s[2048];
    __shared__ int odd_or;
    __shared__ int cnt_s;

    if (tid == 0) { odd_or = 0; cnt_s = 0; }
    __syncthreads();

    // ---- phase 1: int32 interpretation + dtype detect ----
    int my_or = 0;
#pragma unroll
    for (int k = 0; k < 2; ++k) {
        const int n = w * 128 + k * 64 + lane;
        int2 p = ((const int2*)idxw)[n];  // words 2n, 2n+1
        my_or |= p.y;                      // odd word
        const bool match = (n < N) && (p.x == R) && (p.y == C);
        unsigned long long mk = __ballot(match);
        if (lane == 0) masks[w * 2 + k] = mk;
    }
    if (__any(my_or != 0) && lane == 0) odd_or = 1;  // benign multi-write
    __syncthreads();

    if (odd_or == 0) {  // int64 indices: redo ballots from 16B entries
#pragma unroll
        for (int k = 0; k < 2; ++k) {
            const int n = w * 128 + k * 64 + lane;
            int4 p = ((const int4*)idxw)[n];  // words 4n..4n+3
            const bool match = (n < N) && (p.x == R) && (p.z == C);
            unsigned long long mk = __ballot(match);
            if (lane == 0) masks[w * 2 + k] = mk;
        }
        __syncthreads();
    }

    // ---- parallel ordered extraction (wave 0, lanes 0..31) ----
    if (tid < 64) {
        unsigned long long mk = (lane < 32) ? masks[lane] : 0ULL;
        const int pc = __popcll(mk);
        int pre = pc;  // inclusive prefix over lanes 0..31
#pragma unroll
        for (int d = 1; d < 32; d <<= 1) {
            int v = __shfl_up(pre, d, 64);
            if (lane >= d) pre += v;
        }
        int pos = pre - pc;  // exclusive
        const int base = lane * 64;
        while (mk) {
            const int b = __ffsll(mk) - 1;
            list_s[pos++] = (short)(base + b);
            mk &= mk - 1;
        }
        if (lane == 31) cnt_s = pre;
    }
    __syncthreads();
    const int cnt = cnt_s;

    // ---- streaming (identical per-thread structure; full cell, 1 pass) ----
    const size_t obase = (size_t)(R * 64) * ROWSTRIDE4 + (size_t)C * 128;

    if (cnt == 0) {
        const f32x4 z = {0.f, 0.f, 0.f, 0.f};
#pragma unroll
        for (int i = 0; i < 8; ++i) {
            int t = tid + i * 1024;
            __builtin_nontemporal_store(z, &out4[obase + (size_t)(t >> 7) * ROWSTRIDE4 + (t & 127)]);
        }
    } else if (cnt == 1) {
        const f32x4* __restrict__ src = bv4 + (size_t)list_s[0] * BVEC;
#pragma unroll
        for (int i = 0; i < 8; ++i) {
            int t = tid + i * 1024;
            f32x4 v = __builtin_nontemporal_load(&src[t]);
            __builtin_nontemporal_store(v, &out4[obase + (size_t)(t >> 7) * ROWSTRIDE4 + (t & 127)]);
        }
    } else {
        f32x4 acc[8];
#pragma unroll
        for (int i = 0; i < 8; ++i) acc[i] = (f32x4){0.f, 0.f, 0.f, 0.f};
        for (int j = 0; j < cnt; ++j) {
            const f32x4* __restrict__ src = bv4 + (size_t)list_s[j] * BVEC;
#pragma unroll
            for (int i = 0; i < 8; ++i)
                acc[i] += __builtin_nontemporal_load(&src[tid + i * 1024]);
        }
#pragma unroll
        for (int i = 0; i < 8; ++i) {
            int t = tid + i * 1024;
            __builtin_nontemporal_store(acc[i], &out4[obase + (size_t)(t >> 7) * ROWSTRIDE4 + (t & 127)]);
        }
    }
}

// ---------------------------------------------------------------------------
extern "C" void kernel_launch(void* const* d_in, const int* in_sizes, int n_in,
                              void* d_out, int out_size, void* d_ws, size_t ws_size,
                              hipStream_t stream) {
    const float* bv = (const float*)d_in[0];
    const int* idxw = (const int*)d_in[1];
    const int N = in_sizes[1] / 2;  // 2048 blocks

    k_fused<<<NCELLS, 1024, 0, stream>>>(idxw, (const f32x4*)bv,
                                         (f32x4*)d_out, N);
}

// Round 12
// 152.970 us; speedup vs baseline: 1.0539x; 1.0229x over previous
//
#include <hip/hip_runtime.h>

// Problem constants (fixed by setup_inputs): N=2048, B=64, H=W=4096, ks=8
#define GRIDN 64        // block positions per axis (H/B)
#define NCELLS 4096     // GRIDN*GRIDN
#define BVEC 8192       // float4 per block: 64*64*8/4
#define ROWSTRIDE4 8192 // float4 per dense row: W*ks/4

typedef float f32x4 __attribute__((ext_vector_type(4)));

// ---------------------------------------------------------------------------
// Single fused kernel — FINAL config (revert to R9, the measured optimum:
// 153.1 us). 512-thread wgs, grid 8192 = 4096 cells x 2 chunks. Per-wg index
// ballot-scan (2x redundancy — measured optimum vs 4x/1x), parallel ordered
// extraction, three-path NT streaming. Bracketing evidence: 256t/4ch=157.6,
// 1024t/1ch=156.5, plain stores=161.2, 2-kernel=169.7, row-linear=~equal.
__global__ __launch_bounds__(512) void k_fused(const int* __restrict__ idxw,
                                               const f32x4* __restrict__ bv4,
                                               f32x4* __restrict__ out4,
                                               int N) {
    const int cell = blockIdx.x >> 1;
    const int chunk = blockIdx.x & 1;
    const int R = cell >> 6;
    const int C = cell & (GRIDN - 1);
    const int tid = threadIdx.x;
    const int w = tid >> 6;      // wave 0..7
    const int lane = tid & 63;

    __shared__ unsigned long long masks[32];
    __shared__ short list_s[2048];
    __shared__ int odd_or;
    __shared__ int cnt_s;

    if (tid == 0) { odd_or = 0; cnt_s = 0; }
    __syncthreads();

    // ---- phase 1: int32 interpretation + dtype detect ----
    int my_or = 0;
#pragma unroll
    for (int k = 0; k < 4; ++k) {
        const int n = w * 256 + k * 64 + lane;
        int2 p = ((const int2*)idxw)[n];  // words 2n, 2n+1
        my_or |= p.y;                      // odd word
        const bool match = (n < N) && (p.x == R) && (p.y == C);
        unsigned long long mk = __ballot(match);
        if (lane == 0) masks[w * 4 + k] = mk;
    }
    if (__any(my_or != 0) && lane == 0) odd_or = 1;  // benign multi-write
    __syncthreads();

    if (odd_or == 0) {  // int64 indices: redo ballots from 16B entries
#pragma unroll
        for (int k = 0; k < 4; ++k) {
            const int n = w * 256 + k * 64 + lane;
            int4 p = ((const int4*)idxw)[n];  // words 4n..4n+3
            const bool match = (n < N) && (p.x == R) && (p.z == C);
            unsigned long long mk = __ballot(match);
            if (lane == 0) masks[w * 4 + k] = mk;
        }
        __syncthreads();
    }

    // ---- parallel ordered extraction (wave 0, lanes 0..31) ----
    if (tid < 64) {
        unsigned long long mk = (lane < 32) ? masks[lane] : 0ULL;
        const int pc = __popcll(mk);
        int pre = pc;  // inclusive prefix over lanes 0..31
#pragma unroll
        for (int d = 1; d < 32; d <<= 1) {
            int v = __shfl_up(pre, d, 64);
            if (lane >= d) pre += v;
        }
        int pos = pre - pc;  // exclusive
        const int base = lane * 64;
        while (mk) {
            const int b = __ffsll(mk) - 1;
            list_s[pos++] = (short)(base + b);
            mk &= mk - 1;
        }
        if (lane == 31) cnt_s = pre;
    }
    __syncthreads();
    const int cnt = cnt_s;

    // ---- streaming: three paths, NT loads + NT stores ----
    const int tbase = chunk * 4096 + tid;
    const size_t obase = (size_t)(R * 64) * ROWSTRIDE4 + (size_t)C * 128;

    if (cnt == 0) {
        const f32x4 z = {0.f, 0.f, 0.f, 0.f};
#pragma unroll
        for (int i = 0; i < 8; ++i) {
            int t = tbase + i * 512;
            __builtin_nontemporal_store(z, &out4[obase + (size_t)(t >> 7) * ROWSTRIDE4 + (t & 127)]);
        }
    } else if (cnt == 1) {
        const f32x4* __restrict__ src = bv4 + (size_t)list_s[0] * BVEC;
#pragma unroll
        for (int i = 0; i < 8; ++i) {
            int t = tbase + i * 512;
            f32x4 v = __builtin_nontemporal_load(&src[t]);
            __builtin_nontemporal_store(v, &out4[obase + (size_t)(t >> 7) * ROWSTRIDE4 + (t & 127)]);
        }
    } else {
        f32x4 acc[8];
#pragma unroll
        for (int i = 0; i < 8; ++i) acc[i] = (f32x4){0.f, 0.f, 0.f, 0.f};
        for (int j = 0; j < cnt; ++j) {
            const f32x4* __restrict__ src = bv4 + (size_t)list_s[j] * BVEC;
#pragma unroll
            for (int i = 0; i < 8; ++i)
                acc[i] += __builtin_nontemporal_load(&src[tbase + i * 512]);
        }
#pragma unroll
        for (int i = 0; i < 8; ++i) {
            int t = tbase + i * 512;
            __builtin_nontemporal_store(acc[i], &out4[obase + (size_t)(t >> 7) * ROWSTRIDE4 + (t & 127)]);
        }
    }
}

// ---------------------------------------------------------------------------
extern "C" void kernel_launch(void* const* d_in, const int* in_sizes, int n_in,
                              void* d_out, int out_size, void* d_ws, size_t ws_size,
                              hipStream_t stream) {
    const float* bv = (const float*)d_in[0];
    const int* idxw = (const int*)d_in[1];
    const int N = in_sizes[1] / 2;  // 2048 blocks

    k_fused<<<NCELLS * 2, 512, 0, stream>>>(idxw, (const f32x4*)bv,
                                            (f32x4*)d_out, N);
}